// Round 8
// baseline (474.661 us; speedup 1.0000x reference)
//
#include <hip/hip_runtime.h>
#include <hip/hip_bf16.h>
#include <cstdint>
#include <cstddef>

// Problem constants (fixed by reference)
#define T_TOK 8192
#define DDIM  1024
#define FDIM  4096
#define NEXP  8
#define CAP   2048   // int(2.0 * T / E)

typedef __bf16 bf16_t;
typedef __bf16 bf16x8 __attribute__((ext_vector_type(8)));
typedef __bf16 bf16x4 __attribute__((ext_vector_type(4)));
typedef float  f32x4  __attribute__((ext_vector_type(4)));

// async global->LDS: lds dest must be WAVE-UNIFORM base; HW adds lane*16
__device__ __forceinline__ void gload16(const void* g, void* l) {
  __builtin_amdgcn_global_load_lds(
      (const __attribute__((address_space(1))) unsigned int*)g,
      (__attribute__((address_space(3))) unsigned int*)l,
      16, 0, 0);
}

#define VMWAIT(N) asm volatile("s_waitcnt vmcnt(" #N ")" ::: "memory")
#define BARR asm volatile("s_barrier" ::: "memory")

// ---------------- router: logits/softmax/argmax + x->bf16 ----------------
__global__ void router_kernel(const float* __restrict__ x, const float* __restrict__ wsw,
                              const float* __restrict__ bsw, int* __restrict__ routes,
                              float* __restrict__ rpm, float* __restrict__ partial,
                              bf16_t* __restrict__ xbf) {
  const int wv = threadIdx.x >> 6, lane = threadIdx.x & 63;
  const int t = blockIdx.x * 4 + wv;
  const float4* xr = (const float4*)(x + (size_t)t * DDIM);
  float4 xv[4];
  float a[8] = {0.f,0.f,0.f,0.f,0.f,0.f,0.f,0.f};
#pragma unroll
  for (int p = 0; p < 4; ++p) {
    xv[p] = xr[lane + p * 64];
#pragma unroll
    for (int j = 0; j < 4; ++j) {
      float v = ((const float*)&xv[p])[j];
      int d = (lane + p * 64) * 4 + j;
      const float4* wr = (const float4*)(wsw + d * 8);
      float4 w0 = wr[0], w1 = wr[1];
      a[0] += v * w0.x; a[1] += v * w0.y; a[2] += v * w0.z; a[3] += v * w0.w;
      a[4] += v * w1.x; a[5] += v * w1.y; a[6] += v * w1.z; a[7] += v * w1.w;
    }
  }
#pragma unroll
  for (int e = 0; e < 8; ++e) {
#pragma unroll
    for (int off = 32; off > 0; off >>= 1) a[e] += __shfl_xor(a[e], off);
    a[e] += bsw[e];
  }
  float m = a[0]; int arg = 0;
#pragma unroll
  for (int e = 1; e < 8; ++e) { if (a[e] > m) { m = a[e]; arg = e; } }
  float p8[8]; float s = 0.f;
#pragma unroll
  for (int e = 0; e < 8; ++e) { p8[e] = expf(a[e] - m); s += p8[e]; }
  float inv_s = 1.f / s;   // = softmax max since p[arg]=1
  bf16_t* xbr = xbf + (size_t)t * DDIM;
#pragma unroll
  for (int p = 0; p < 4; ++p) {
    int i4 = lane + p * 64;
    bf16x4 hb;
    hb[0] = (bf16_t)xv[p].x; hb[1] = (bf16_t)xv[p].y;
    hb[2] = (bf16_t)xv[p].z; hb[3] = (bf16_t)xv[p].w;
    *(bf16x4*)(xbr + (size_t)i4 * 4) = hb;
  }
  __shared__ float pp[4][8];
  if (lane == 0) {
    routes[t] = arg;
    rpm[t] = inv_s;
#pragma unroll
    for (int e = 0; e < 8; ++e) pp[wv][e] = p8[e] * inv_s;
  }
  __syncthreads();
  if (threadIdx.x < 8) {
    int e = threadIdx.x;
    partial[(size_t)blockIdx.x * 8 + e] = pp[0][e] + pp[1][e] + pp[2][e] + pp[3][e];
  }
}

// ---------------- deterministic reduce of per-block prob sums ----------------
__global__ void reduce_partials_kernel(const float* __restrict__ partial,
                                       float* __restrict__ out_rps) {
  int tid = threadIdx.x;           // 256
  int e = tid & 7, j0 = tid >> 3;  // 32 lanes per expert
  float s = 0.f;
  for (int j = j0; j < 2048; j += 32) s += partial[j * 8 + e];
  __shared__ float red[256];
  red[tid] = s;
  __syncthreads();
  if (tid < 8) {
    float t = 0.f;
    for (int k = 0; k < 32; ++k) t += red[tid + 8 * k];
    out_rps[tid] = t;
  }
}

// ---------------- queue-position scan + dispatch index + drop list ----------------
__global__ void scan_kernel(const int* __restrict__ routes, int* __restrict__ inv,
                            int* __restrict__ counts_i, float* __restrict__ out_counts,
                            float* __restrict__ out_ndrop, int* __restrict__ drop_list,
                            int* __restrict__ ndrop_i) {
  __shared__ int scnt[256][8];
  __shared__ int raw[8];
  __shared__ int dropc;
  int tid = threadIdx.x;
  for (int i = tid; i < NEXP * CAP; i += 256) inv[i] = 0;   // zero (incl. padded tail)
  if (tid == 0) dropc = 0;
  int myr[32];
  int cnt[8] = {0,0,0,0,0,0,0,0};
  int tbase = tid * 32;
  for (int i = 0; i < 32; ++i) { int r = routes[tbase + i]; myr[i] = r; cnt[r]++; }
#pragma unroll
  for (int e = 0; e < 8; ++e) scnt[tid][e] = cnt[e];
  __syncthreads();
  if (tid < 8) {
    int run = 0;
    for (int j = 0; j < 256; ++j) { int v = scnt[j][tid]; scnt[j][tid] = run; run += v; }
    raw[tid] = run;
  }
  __syncthreads();
  int base[8];
#pragma unroll
  for (int e = 0; e < 8; ++e) base[e] = scnt[tid][e];
  for (int i = 0; i < 32; ++i) {
    int r = myr[i];
    int p = base[r]++;
    if (p < CAP) inv[r * CAP + p] = tbase + i;
    else         drop_list[atomicAdd(&dropc, 1)] = tbase + i;
  }
  if (tid < 8) {
    int c = min(raw[tid], CAP);
    counts_i[tid] = c;
    out_counts[tid] = (float)c;
  }
  __syncthreads();
  if (tid == 0) {
    *ndrop_i = dropc;
    *out_ndrop = (float)dropc;
  }
}

// ---------------- fill only dropped tokens: out[t] = x[t]*rpm[t] ----------------
__global__ void fill_dropped_kernel(const int* __restrict__ drop_list, const int* __restrict__ ndrop_i,
                                    const float* __restrict__ x, const float* __restrict__ rpm,
                                    float* __restrict__ outf) {
  int total = (*ndrop_i) * 256;    // float4s per dropped token row
  for (int i = blockIdx.x * blockDim.x + threadIdx.x; i < total; i += gridDim.x * blockDim.x) {
    int t = drop_list[i >> 8];
    int j = i & 255;
    float r = rpm[t];
    float4 v = ((const float4*)(x + (size_t)t * DDIM))[j];
    float4 o = {v.x * r, v.y * r, v.z * r, v.w * r};
    ((float4*)(outf + (size_t)t * DDIM))[j] = o;
  }
}

// ---------------- fused transpose+convert for W1 and W2 in one launch ----------------
__global__ void transpose_both_kernel(const float* __restrict__ W1, const float* __restrict__ W2,
                                      bf16_t* __restrict__ W1T, bf16_t* __restrict__ W2T,
                                      int nb, int e0) {
  const int z = blockIdx.z;
  const float* s; bf16_t* d; int R, C, bx, by;
  if (z < nb) {
    s = W1 + (size_t)(e0 + z) * ((size_t)DDIM * FDIM);
    d = W1T + (size_t)z * ((size_t)DDIM * FDIM);
    R = DDIM; C = FDIM; bx = blockIdx.x * 64; by = blockIdx.y * 64;
  } else {
    s = W2 + (size_t)(e0 + z - nb) * ((size_t)FDIM * DDIM);
    d = W2T + (size_t)(z - nb) * ((size_t)FDIM * DDIM);
    R = FDIM; C = DDIM; bx = blockIdx.y * 64; by = blockIdx.x * 64;
  }
  __shared__ float tile[64][65];
  int c4 = (threadIdx.x & 15) * 4;
  int r0 = threadIdx.x >> 4;
#pragma unroll
  for (int p = 0; p < 4; ++p) {
    int r = r0 + p * 16;
    float4 v = *(const float4*)&s[(size_t)(by + r) * C + bx + c4];
    tile[r][c4] = v.x; tile[r][c4 + 1] = v.y; tile[r][c4 + 2] = v.z; tile[r][c4 + 3] = v.w;
  }
  __syncthreads();
  int r8 = (threadIdx.x & 7) * 8;
  int cw = threadIdx.x >> 3;
#pragma unroll
  for (int p = 0; p < 2; ++p) {
    int c = cw + p * 32;
    bf16x8 o;
#pragma unroll
    for (int j = 0; j < 8; ++j) o[j] = (bf16_t)tile[r8 + j][c];
    *(bf16x8*)&d[(size_t)(bx + c) * R + by + r8] = o;
  }
}

// ============ MFMA GEMM: BMx256, BK=64, 8 waves, bulk-prefetch dbuf ============
// Identical geometry/swizzle/epilogue to R7 (passing). Schedule change only:
// dbuf d^1 is entirely DEAD during tile t (tile t-1's reads completed before
// t's first barrier), so ALL FOUR stage units of tile t+1 are issued at P1 and
// the single vmcnt(0) sits AFTER P4's MFMA (WAIT2 slot) — issue->wait distance
// ~3.7 phase bodies (~1500-2300cy) covers HBM ~900cy. The P4-end barrier then
// publishes the DMA to all waves before tile t+1's P1 ds_reads. R7's counted
// waits (VMWAIT(2) one phase after issue) exposed ~500cy stalls twice per tile.
template <int KDIM, int MODE, int BM>
__launch_bounds__(512, 2)
__global__ void gemm8p_kernel(const bf16_t* __restrict__ Abase, const bf16_t* __restrict__ Bbase,
                              const int* __restrict__ inv, const int* __restrict__ counts_i,
                              const float* __restrict__ bias_all, const float* __restrict__ rpm,
                              void* __restrict__ outp, int e0) {
  constexpr int MDIM = (MODE == 1) ? FDIM : DDIM;
  constexpr int NT = KDIM / 64;
  constexpr int MF = BM / 32;            // M-frags per wave (8 or 4)
  constexpr int AH = (BM / 2) * 128;     // A-half bytes per dbuf (16KB or 8KB)
  constexpr int AU = AH / 8192;          // gloads/thread per A-half (2 or 1)
  constexpr int BB = 4 * AH;             // B region base
  extern __shared__ char smem[];

  // T1: XCD-chunked bijective swizzle (nwg % 8 == 0 by construction)
  const int nx = gridDim.x, ny = gridDim.y;
  const int nwg = nx * ny * gridDim.z;
  const int flat = blockIdx.x + nx * (blockIdx.y + ny * blockIdx.z);
  const int nf = (flat & 7) * (nwg >> 3) + (flat >> 3);
  const int bx = nf % nx;
  const int tmp = nf / nx;
  const int by = tmp % ny, bz = tmp / ny;

  const int e = e0 + bz;
  const int cnt = counts_i[e];
  const int c0 = bx * 256;
  if (c0 >= cnt) return;                 // uniform early-exit before any barrier
  const int m0 = by * BM;

  const bf16_t* A = Abase + (size_t)bz * ((size_t)MDIM * KDIM);
  const float* bias = bias_all + (size_t)e * MDIM;

  const int tid = threadIdx.x, lane = tid & 63, w = tid >> 6;
  const int l15 = lane & 15, l4 = lane >> 4;
  const int wm = w >> 2, wn = w & 3;

  // ---- stage sources (pre-swizzled global element offsets / pointers) ----
  size_t aSrc[2][AU];
#pragma unroll
  for (int mh = 0; mh < 2; ++mh)
#pragma unroll
    for (int u = 0; u < AU; ++u) {
      int r = u * 64 + (tid >> 3);                    // row within half
      int g = (tid & 7) ^ (r & 7);                    // logical granule for my slot
      aSrc[mh][u] = (size_t)(m0 + mh * (BM / 2) + r) * KDIM + g * 8;
    }
  const bf16_t* bSrc[2][2];
#pragma unroll
  for (int nh = 0; nh < 2; ++nh)
#pragma unroll
    for (int u = 0; u < 2; ++u) {
      int cb = u * 64 + (tid >> 3);                   // col within half
      int g = (tid & 7) ^ (cb & 7);
      int c = c0 + nh * 128 + cb;
      if (MODE == 1) {
        int tok = inv[e * CAP + c];                   // zeroed tail -> token 0 (unread)
        bSrc[nh][u] = Bbase + (size_t)tok * KDIM + g * 8;
      } else {
        bSrc[nh][u] = Bbase + (size_t)bz * ((size_t)CAP * KDIM) + (size_t)c * KDIM + g * 8;
      }
    }

  // ---- swizzled read offsets ----
  int aRd[MF][2];
#pragma unroll
  for (int mi = 0; mi < MF; ++mi) {
    int r = mi * 16 + l15;                            // row within my half
#pragma unroll
    for (int ks = 0; ks < 2; ++ks)
      aRd[mi][ks] = r * 128 + (((ks * 4 + l4) ^ (r & 7)) << 4);
  }
  int bOff[4][2];
#pragma unroll
  for (int nj = 0; nj < 4; ++nj) {
    int ch = (nj & 1) * 64 + wn * 16 + l15;           // col within half
#pragma unroll
    for (int ks = 0; ks < 2; ++ks)
      bOff[nj][ks] = (nj >> 1) * 16384 + ch * 128 + (((ks * 4 + l4) ^ (ch & 7)) << 4);
  }

  auto stageA = [&](int t, int mh) {
#pragma unroll
    for (int u = 0; u < AU; ++u)
      gload16(A + aSrc[mh][u] + (size_t)t * 64,
              smem + (t & 1) * (2 * AH) + mh * AH + u * 8192 + w * 1024);
  };
  auto stageB = [&](int t, int nh) {
#pragma unroll
    for (int u = 0; u < 2; ++u)
      gload16(bSrc[nh][u] + (size_t)t * 64,
              smem + BB + (t & 1) * 32768 + nh * 16384 + u * 8192 + w * 1024);
  };

  f32x4 acc[MF][4];
#pragma unroll
  for (int i = 0; i < MF; ++i)
#pragma unroll
    for (int j = 0; j < 4; ++j) acc[i][j] = (f32x4){0.f, 0.f, 0.f, 0.f};
  bf16x8 af[MF], bv[2];

#define PHASE(D, KS, NH, DOA, STAGECODE, WAIT2CODE)                             \
  {                                                                             \
    if (DOA) {                                                                  \
      const char* sa_ = smem + (D) * (2 * AH) + wm * AH;                        \
      _Pragma("unroll") for (int mi = 0; mi < MF; ++mi)                         \
          af[mi] = *(const bf16x8*)(sa_ + aRd[mi][KS]);                         \
    }                                                                           \
    {                                                                           \
      const char* sb_ = smem + BB + (D) * 32768;                                \
      bv[0] = *(const bf16x8*)(sb_ + bOff[2 * (NH)][KS]);                       \
      bv[1] = *(const bf16x8*)(sb_ + bOff[2 * (NH) + 1][KS]);                   \
    }                                                                           \
    STAGECODE;                                                                  \
    BARR;                                                                       \
    __builtin_amdgcn_s_setprio(1);                                              \
    _Pragma("unroll") for (int mi = 0; mi < MF; ++mi) {                         \
      acc[mi][2 * (NH)] = __builtin_amdgcn_mfma_f32_16x16x32_bf16(              \
          af[mi], bv[0], acc[mi][2 * (NH)], 0, 0, 0);                           \
      acc[mi][2 * (NH) + 1] = __builtin_amdgcn_mfma_f32_16x16x32_bf16(          \
          af[mi], bv[1], acc[mi][2 * (NH) + 1], 0, 0, 0);                       \
    }                                                                           \
    __builtin_amdgcn_s_setprio(0);                                              \
    WAIT2CODE;                                                                  \
    BARR;                                                                       \
  }

  // prologue: full tile 0; drain; barrier
  stageA(0, 0); stageA(0, 1); stageB(0, 0); stageB(0, 1);
  VMWAIT(0);
  BARR;

  for (int t = 0; t < NT; ++t) {
    const int d = t & 1;
    if (t + 1 < NT) {
      const int tn = t + 1;
      // P1: bulk-stage ALL of tile t+1 into dbuf d^1 (dead since tile t-1's end)
      PHASE(d, 0, 0, 1, { stageA(tn, 0); stageA(tn, 1); stageB(tn, 0); stageB(tn, 1); }, {});
      PHASE(d, 0, 1, 0, {}, {});
      PHASE(d, 1, 0, 1, {}, {});
      PHASE(d, 1, 1, 0, {}, { VMWAIT(0); });   // ~3.7 phases after issue; BARR publishes
    } else {
      PHASE(d, 0, 0, 1, {}, {});
      PHASE(d, 0, 1, 0, {}, {});
      PHASE(d, 1, 0, 1, {}, {});
      PHASE(d, 1, 1, 0, {}, {});
    }
  }
#undef PHASE

  // ---- epilogue: D layout col=lane&15, row=(lane>>4)*4+reg [verified m89/m91] ----
  if constexpr (MODE == 1) {
    bf16_t* h = (bf16_t*)outp + (size_t)bz * ((size_t)CAP * FDIM);
#pragma unroll
    for (int nj = 0; nj < 4; ++nj) {
      int c = c0 + nj * 64 + wn * 16 + l15;
      bf16_t* hrow = h + (size_t)c * FDIM;
#pragma unroll
      for (int mi = 0; mi < MF; ++mi) {
        int f = m0 + wm * (BM / 2) + mi * 16 + l4 * 4;
        const float4 bi = *(const float4*)&bias[f];
        f32x4 v = acc[mi][nj];
        bf16x4 hv;
        hv[0] = (bf16_t)fmaxf(v[0] + bi.x, 0.f);
        hv[1] = (bf16_t)fmaxf(v[1] + bi.y, 0.f);
        hv[2] = (bf16_t)fmaxf(v[2] + bi.z, 0.f);
        hv[3] = (bf16_t)fmaxf(v[3] + bi.w, 0.f);
        *(bf16x4*)&hrow[f] = hv;
      }
    }
  } else {
    float* finalp = (float*)outp;
#pragma unroll
    for (int nj = 0; nj < 4; ++nj) {
      int c = c0 + nj * 64 + wn * 16 + l15;
      if (c < cnt) {
        int tok = inv[e * CAP + c];
        float r = rpm[tok];
        float* orow = finalp + (size_t)tok * DDIM;
#pragma unroll
        for (int mi = 0; mi < MF; ++mi) {
          int dd = m0 + wm * (BM / 2) + mi * 16 + l4 * 4;
          const float4 bi = *(const float4*)&bias[dd];
          f32x4 v = acc[mi][nj];
          float4 o;
          o.x = (v[0] + bi.x) * r;
          o.y = (v[1] + bi.y) * r;
          o.z = (v[2] + bi.z) * r;
          o.w = (v[3] + bi.w) * r;
          *(float4*)&orow[dd] = o;
        }
      }
    }
  }
}

// ---------------- host launcher ----------------
extern "C" void kernel_launch(void* const* d_in, const int* in_sizes, int n_in,
                              void* d_out, int out_size, void* d_ws, size_t ws_size,
                              hipStream_t stream) {
  (void)in_sizes; (void)n_in; (void)out_size;
  const float* x   = (const float*)d_in[0];
  const float* wsw = (const float*)d_in[1];
  const float* bsw = (const float*)d_in[2];
  const float* W1  = (const float*)d_in[3];
  const float* b1  = (const float*)d_in[4];
  const float* W2  = (const float*)d_in[5];
  const float* b2  = (const float*)d_in[6];

  float* out_final  = (float*)d_out;            // [T][D]
  float* out_counts = out_final + 8388608;      // [8]
  float* out_rps    = out_final + 8388616;      // [8]
  float* out_ndrop  = out_final + 8388624;      // [1]
  float* out_rpm    = out_final + 8388625;      // [T] (output 5 of reference)

  char* ws = (char*)d_ws;
  size_t off = 0;
  auto carve = [&](size_t bytes) {
    char* p = ws + off;
    off += (bytes + 255) & ~(size_t)255;
    return p;
  };
  bf16_t* xbf      = (bf16_t*)carve((size_t)T_TOK * DDIM * 2);   // 16 MB
  int*    routes   = (int*)   carve((size_t)T_TOK * 4);
  int*    inv      = (int*)   carve((size_t)NEXP * CAP * 4);
  int*    counts_i = (int*)   carve((size_t)NEXP * 4);
  float*  partial  = (float*) carve((size_t)2048 * 8 * 4);
  int*    drop_list= (int*)   carve((size_t)T_TOK * 4);
  int*    ndrop_i  = (int*)   carve(256);
  size_t fixed = off;
  const size_t PER_E = 2 * (size_t)FDIM * DDIM * 2 + (size_t)CAP * FDIM * 2; // 32MB
  int nb = 8;
  while (nb > 1 && fixed + (size_t)nb * PER_E > ws_size) nb >>= 1;
  bf16_t* W1T  = (bf16_t*)carve((size_t)nb * FDIM * DDIM * 2);
  bf16_t* W2T  = (bf16_t*)carve((size_t)nb * DDIM * FDIM * 2);
  bf16_t* hbuf = (bf16_t*)carve((size_t)nb * CAP * FDIM * 2);

  // >64KB dynamic LDS opt-in (runtime attr; graph-capture safe)
  hipFuncSetAttribute((const void*)gemm8p_kernel<DDIM, 1, 256>,
                      hipFuncAttributeMaxDynamicSharedMemorySize, 131072);
  hipFuncSetAttribute((const void*)gemm8p_kernel<FDIM, 2, 128>,
                      hipFuncAttributeMaxDynamicSharedMemorySize, 98304);

  router_kernel<<<T_TOK / 4, 256, 0, stream>>>(x, wsw, bsw, routes, out_rpm, partial, xbf);
  reduce_partials_kernel<<<1, 256, 0, stream>>>(partial, out_rps);
  scan_kernel<<<1, 256, 0, stream>>>(routes, inv, counts_i, out_counts, out_ndrop,
                                     drop_list, ndrop_i);
  fill_dropped_kernel<<<256, 256, 0, stream>>>(drop_list, ndrop_i, x, out_rpm, out_final);

  for (int e0 = 0; e0 < NEXP; e0 += nb) {
    transpose_both_kernel<<<dim3(64, 16, 2 * nb), 256, 0, stream>>>(W1, W2, W1T, W2T, nb, e0);
    gemm8p_kernel<DDIM, 1, 256><<<dim3(CAP / 256, FDIM / 256, nb), 512, 131072, stream>>>(
        W1T, xbf, inv, counts_i, b1, nullptr, hbuf, e0);
    gemm8p_kernel<FDIM, 2, 128><<<dim3(CAP / 256, DDIM / 128, nb), 512, 98304, stream>>>(
        W2T, hbuf, inv, counts_i, b2, out_rpm, d_out, e0);
  }
}

// Round 9
// 418.782 us; speedup vs baseline: 1.1334x; 1.1334x over previous
//
#include <hip/hip_runtime.h>
#include <hip/hip_bf16.h>
#include <cstdint>
#include <cstddef>

// Problem constants (fixed by reference)
#define T_TOK 8192
#define DDIM  1024
#define FDIM  4096
#define NEXP  8
#define CAP   2048   // int(2.0 * T / E)

typedef __bf16 bf16_t;
typedef __bf16 bf16x8 __attribute__((ext_vector_type(8)));
typedef __bf16 bf16x4 __attribute__((ext_vector_type(4)));
typedef float  f32x4  __attribute__((ext_vector_type(4)));

// async global->LDS: lds dest must be WAVE-UNIFORM base; HW adds lane*16
__device__ __forceinline__ void gload16(const void* g, void* l) {
  __builtin_amdgcn_global_load_lds(
      (const __attribute__((address_space(1))) unsigned int*)g,
      (__attribute__((address_space(3))) unsigned int*)l,
      16, 0, 0);
}

#define VMWAIT(N) asm volatile("s_waitcnt vmcnt(" #N ")" ::: "memory")
#define BARR asm volatile("s_barrier" ::: "memory")

// ---------------- router: logits/softmax/argmax + x->bf16 ----------------
__global__ void router_kernel(const float* __restrict__ x, const float* __restrict__ wsw,
                              const float* __restrict__ bsw, int* __restrict__ routes,
                              float* __restrict__ rpm, float* __restrict__ partial,
                              bf16_t* __restrict__ xbf) {
  const int wv = threadIdx.x >> 6, lane = threadIdx.x & 63;
  const int t = blockIdx.x * 4 + wv;
  const float4* xr = (const float4*)(x + (size_t)t * DDIM);
  float4 xv[4];
  float a[8] = {0.f,0.f,0.f,0.f,0.f,0.f,0.f,0.f};
#pragma unroll
  for (int p = 0; p < 4; ++p) {
    xv[p] = xr[lane + p * 64];
#pragma unroll
    for (int j = 0; j < 4; ++j) {
      float v = ((const float*)&xv[p])[j];
      int d = (lane + p * 64) * 4 + j;
      const float4* wr = (const float4*)(wsw + d * 8);
      float4 w0 = wr[0], w1 = wr[1];
      a[0] += v * w0.x; a[1] += v * w0.y; a[2] += v * w0.z; a[3] += v * w0.w;
      a[4] += v * w1.x; a[5] += v * w1.y; a[6] += v * w1.z; a[7] += v * w1.w;
    }
  }
#pragma unroll
  for (int e = 0; e < 8; ++e) {
#pragma unroll
    for (int off = 32; off > 0; off >>= 1) a[e] += __shfl_xor(a[e], off);
    a[e] += bsw[e];
  }
  float m = a[0]; int arg = 0;
#pragma unroll
  for (int e = 1; e < 8; ++e) { if (a[e] > m) { m = a[e]; arg = e; } }
  float p8[8]; float s = 0.f;
#pragma unroll
  for (int e = 0; e < 8; ++e) { p8[e] = expf(a[e] - m); s += p8[e]; }
  float inv_s = 1.f / s;   // = softmax max since p[arg]=1
  bf16_t* xbr = xbf + (size_t)t * DDIM;
#pragma unroll
  for (int p = 0; p < 4; ++p) {
    int i4 = lane + p * 64;
    bf16x4 hb;
    hb[0] = (bf16_t)xv[p].x; hb[1] = (bf16_t)xv[p].y;
    hb[2] = (bf16_t)xv[p].z; hb[3] = (bf16_t)xv[p].w;
    *(bf16x4*)(xbr + (size_t)i4 * 4) = hb;
  }
  __shared__ float pp[4][8];
  if (lane == 0) {
    routes[t] = arg;
    rpm[t] = inv_s;
#pragma unroll
    for (int e = 0; e < 8; ++e) pp[wv][e] = p8[e] * inv_s;
  }
  __syncthreads();
  if (threadIdx.x < 8) {
    int e = threadIdx.x;
    partial[(size_t)blockIdx.x * 8 + e] = pp[0][e] + pp[1][e] + pp[2][e] + pp[3][e];
  }
}

// ---------------- deterministic reduce of per-block prob sums ----------------
__global__ void reduce_partials_kernel(const float* __restrict__ partial,
                                       float* __restrict__ out_rps) {
  int tid = threadIdx.x;           // 256
  int e = tid & 7, j0 = tid >> 3;  // 32 lanes per expert
  float s = 0.f;
  for (int j = j0; j < 2048; j += 32) s += partial[j * 8 + e];
  __shared__ float red[256];
  red[tid] = s;
  __syncthreads();
  if (tid < 8) {
    float t = 0.f;
    for (int k = 0; k < 32; ++k) t += red[tid + 8 * k];
    out_rps[tid] = t;
  }
}

// ---------------- queue-position scan + dispatch index + drop list ----------------
__global__ void scan_kernel(const int* __restrict__ routes, int* __restrict__ inv,
                            int* __restrict__ counts_i, float* __restrict__ out_counts,
                            float* __restrict__ out_ndrop, int* __restrict__ drop_list,
                            int* __restrict__ ndrop_i) {
  __shared__ int scnt[256][8];
  __shared__ int raw[8];
  __shared__ int dropc;
  int tid = threadIdx.x;
  for (int i = tid; i < NEXP * CAP; i += 256) inv[i] = 0;   // zero (incl. padded tail)
  if (tid == 0) dropc = 0;
  int myr[32];
  int cnt[8] = {0,0,0,0,0,0,0,0};
  int tbase = tid * 32;
  for (int i = 0; i < 32; ++i) { int r = routes[tbase + i]; myr[i] = r; cnt[r]++; }
#pragma unroll
  for (int e = 0; e < 8; ++e) scnt[tid][e] = cnt[e];
  __syncthreads();
  if (tid < 8) {
    int run = 0;
    for (int j = 0; j < 256; ++j) { int v = scnt[j][tid]; scnt[j][tid] = run; run += v; }
    raw[tid] = run;
  }
  __syncthreads();
  int base[8];
#pragma unroll
  for (int e = 0; e < 8; ++e) base[e] = scnt[tid][e];
  for (int i = 0; i < 32; ++i) {
    int r = myr[i];
    int p = base[r]++;
    if (p < CAP) inv[r * CAP + p] = tbase + i;
    else         drop_list[atomicAdd(&dropc, 1)] = tbase + i;
  }
  if (tid < 8) {
    int c = min(raw[tid], CAP);
    counts_i[tid] = c;
    out_counts[tid] = (float)c;
  }
  __syncthreads();
  if (tid == 0) {
    *ndrop_i = dropc;
    *out_ndrop = (float)dropc;
  }
}

// ---------------- fill only dropped tokens: out[t] = x[t]*rpm[t] ----------------
__global__ void fill_dropped_kernel(const int* __restrict__ drop_list, const int* __restrict__ ndrop_i,
                                    const float* __restrict__ x, const float* __restrict__ rpm,
                                    float* __restrict__ outf) {
  int total = (*ndrop_i) * 256;    // float4s per dropped token row
  for (int i = blockIdx.x * blockDim.x + threadIdx.x; i < total; i += gridDim.x * blockDim.x) {
    int t = drop_list[i >> 8];
    int j = i & 255;
    float r = rpm[t];
    float4 v = ((const float4*)(x + (size_t)t * DDIM))[j];
    float4 o = {v.x * r, v.y * r, v.z * r, v.w * r};
    ((float4*)(outf + (size_t)t * DDIM))[j] = o;
  }
}

// ---------------- fused transpose+convert for W1 and W2 in one launch ----------------
__global__ void transpose_both_kernel(const float* __restrict__ W1, const float* __restrict__ W2,
                                      bf16_t* __restrict__ W1T, bf16_t* __restrict__ W2T,
                                      int nb, int e0) {
  const int z = blockIdx.z;
  const float* s; bf16_t* d; int R, C, bx, by;
  if (z < nb) {
    s = W1 + (size_t)(e0 + z) * ((size_t)DDIM * FDIM);
    d = W1T + (size_t)z * ((size_t)DDIM * FDIM);
    R = DDIM; C = FDIM; bx = blockIdx.x * 64; by = blockIdx.y * 64;
  } else {
    s = W2 + (size_t)(e0 + z - nb) * ((size_t)FDIM * DDIM);
    d = W2T + (size_t)(z - nb) * ((size_t)FDIM * DDIM);
    R = FDIM; C = DDIM; bx = blockIdx.y * 64; by = blockIdx.x * 64;
  }
  __shared__ float tile[64][65];
  int c4 = (threadIdx.x & 15) * 4;
  int r0 = threadIdx.x >> 4;
#pragma unroll
  for (int p = 0; p < 4; ++p) {
    int r = r0 + p * 16;
    float4 v = *(const float4*)&s[(size_t)(by + r) * C + bx + c4];
    tile[r][c4] = v.x; tile[r][c4 + 1] = v.y; tile[r][c4 + 2] = v.z; tile[r][c4 + 3] = v.w;
  }
  __syncthreads();
  int r8 = (threadIdx.x & 7) * 8;
  int cw = threadIdx.x >> 3;
#pragma unroll
  for (int p = 0; p < 2; ++p) {
    int c = cw + p * 32;
    bf16x8 o;
#pragma unroll
    for (int j = 0; j < 8; ++j) o[j] = (bf16_t)tile[r8 + j][c];
    *(bf16x8*)&d[(size_t)(bx + c) * R + by + r8] = o;
  }
}

// ============ MFMA GEMM: 128x128 tile, BK=64, 4 waves, 2 blocks/CU ============
// D[m][c] = sum_k A[m][k]*B[c][k] (row-major K-contiguous operands).
// 4 waves 2M x 2N, per-wave 64x64 = 4x4 frags of 16x16. LDS 64KB static:
//   A [2dbuf][128 rows][128B] (32KB) then B [2dbuf][128 cols][128B] (32KB).
// ONE sync point per K-tile: stage(t+1) at tile start into dead dbuf; compute
// tile t (2 ksteps x 16 MFMA, no barriers -> waves slip, LDS/MFMA overlap
// across waves AND across the 2 resident blocks); then vmcnt(0)+s_barrier
// publishes tile t+1. Hazards: RAW covered by per-wave drain + barrier; WAR:
// stage targets dbuf whose reads all completed before the PREVIOUS barrier.
// Swizzle: 16B slot s at row r holds K-granule s^(r&7); frag reads use slot
// (ks*4+l4)^(r&7) -> 2-way bank aliasing (free, m136).
// Stage map: thread tid, unit u: row u*32+(tid>>3), slot tid&7; LDS dest
// u*4096 + w*1024 (+lane*16 by HW) == tid*16 within unit  [exact identity].
// MODE 1: A=W1T[F][D], B=xbf gathered via inv -> relu(+b1) -> h bf16
// MODE 2: A=W2T[D][F], B=h                    -> (+b2)*rpm scattered -> final f32
template <int KDIM, int MODE>
__launch_bounds__(256, 2)
__global__ void gemm_kernel(const bf16_t* __restrict__ Abase, const bf16_t* __restrict__ Bbase,
                            const int* __restrict__ inv, const int* __restrict__ counts_i,
                            const float* __restrict__ bias_all, const float* __restrict__ rpm,
                            void* __restrict__ outp, int e0) {
  constexpr int MDIM = (MODE == 1) ? FDIM : DDIM;
  constexpr int NT = KDIM / 64;
  __shared__ __align__(16) char smem[65536];

  // T1: XCD-chunked bijective swizzle (nwg % 8 == 0 by construction):
  // XCD x (= hw flat%8) owns contiguous tile range [x*nwg/8, ...) -> A-panel reuse in L2
  const int nx = gridDim.x, ny = gridDim.y;
  const int nwg = nx * ny * gridDim.z;
  const int flat = blockIdx.x + nx * (blockIdx.y + ny * blockIdx.z);
  const int nf = (flat & 7) * (nwg >> 3) + (flat >> 3);
  const int bx = nf % nx;
  const int tmp = nf / nx;
  const int by = tmp % ny, bz = tmp / ny;

  const int e = e0 + bz;
  const int cnt = counts_i[e];
  const int c0 = bx * 128;
  if (c0 >= cnt) return;                 // uniform early-exit before any barrier
  const int m0 = by * 128;

  const bf16_t* A = Abase + (size_t)bz * ((size_t)MDIM * KDIM);
  const float* bias = bias_all + (size_t)e * MDIM;

  const int tid = threadIdx.x, lane = tid & 63, w = tid >> 6;
  const int l15 = lane & 15, l4 = lane >> 4;
  const int wm = w >> 1, wn = w & 1;

  // ---- stage sources (pre-swizzled global element offsets / pointers) ----
  size_t aOff[4];
#pragma unroll
  for (int u = 0; u < 4; ++u) {
    int r = u * 32 + (tid >> 3);
    int g = (tid & 7) ^ (r & 7);
    aOff[u] = (size_t)(m0 + r) * KDIM + g * 8;
  }
  const bf16_t* bPtr[4];
#pragma unroll
  for (int v = 0; v < 4; ++v) {
    int c = v * 32 + (tid >> 3);
    int g = (tid & 7) ^ (c & 7);
    if (MODE == 1) {
      int tok = inv[e * CAP + c0 + c];   // zeroed tail -> token 0 (result unread)
      bPtr[v] = Bbase + (size_t)tok * KDIM + g * 8;
    } else {
      bPtr[v] = Bbase + (size_t)bz * ((size_t)CAP * KDIM) + (size_t)(c0 + c) * KDIM + g * 8;
    }
  }

  // ---- swizzled read offsets (within dbuf) ----
  int aRd[4][2], bRd[4][2];
#pragma unroll
  for (int mi = 0; mi < 4; ++mi) {
    int r = wm * 64 + mi * 16 + l15;
#pragma unroll
    for (int ks = 0; ks < 2; ++ks)
      aRd[mi][ks] = r * 128 + (((ks * 4 + l4) ^ (r & 7)) << 4);
  }
#pragma unroll
  for (int nj = 0; nj < 4; ++nj) {
    int c = wn * 64 + nj * 16 + l15;
#pragma unroll
    for (int ks = 0; ks < 2; ++ks)
      bRd[nj][ks] = c * 128 + (((ks * 4 + l4) ^ (c & 7)) << 4);
  }

  auto stage = [&](int t) {
    char* sa = smem + (t & 1) * 16384 + w * 1024;
    char* sb = smem + 32768 + (t & 1) * 16384 + w * 1024;
#pragma unroll
    for (int u = 0; u < 4; ++u) gload16(A + aOff[u] + t * 64, sa + u * 4096);
#pragma unroll
    for (int v = 0; v < 4; ++v) gload16(bPtr[v] + t * 64, sb + v * 4096);
  };

  f32x4 acc[4][4];
#pragma unroll
  for (int i = 0; i < 4; ++i)
#pragma unroll
    for (int j = 0; j < 4; ++j) acc[i][j] = (f32x4){0.f, 0.f, 0.f, 0.f};

  // prologue: stage tile 0, drain, publish
  stage(0);
  VMWAIT(0);
  BARR;

  for (int t = 0; t < NT; ++t) {
    const int d = t & 1;
    const bool more = (t + 1 < NT);
    if (more) stage(t + 1);              // into dead dbuf d^1
    const char* sa = smem + d * 16384;
    const char* sb = smem + 32768 + d * 16384;
#pragma unroll
    for (int ks = 0; ks < 2; ++ks) {
      bf16x8 af[4], bf[4];
#pragma unroll
      for (int mi = 0; mi < 4; ++mi) af[mi] = *(const bf16x8*)(sa + aRd[mi][ks]);
#pragma unroll
      for (int nj = 0; nj < 4; ++nj) bf[nj] = *(const bf16x8*)(sb + bRd[nj][ks]);
#pragma unroll
      for (int mi = 0; mi < 4; ++mi)
#pragma unroll
        for (int nj = 0; nj < 4; ++nj)
          acc[mi][nj] = __builtin_amdgcn_mfma_f32_16x16x32_bf16(af[mi], bf[nj], acc[mi][nj], 0, 0, 0);
    }
    if (more) {
      VMWAIT(0);                         // drains stage(t+1) issued one full tile ago
      BARR;                              // publish to all waves
    }
  }

  // ---- epilogue: D layout col=lane&15, row=(lane>>4)*4+reg [verified m89/m91] ----
  if constexpr (MODE == 1) {
    bf16_t* h = (bf16_t*)outp + (size_t)bz * ((size_t)CAP * FDIM);
#pragma unroll
    for (int nj = 0; nj < 4; ++nj) {
      int c = c0 + wn * 64 + nj * 16 + l15;
      bf16_t* hrow = h + (size_t)c * FDIM;
#pragma unroll
      for (int mi = 0; mi < 4; ++mi) {
        int f = m0 + wm * 64 + mi * 16 + l4 * 4;
        const float4 bi = *(const float4*)&bias[f];
        f32x4 v = acc[mi][nj];
        bf16x4 hv;
        hv[0] = (bf16_t)fmaxf(v[0] + bi.x, 0.f);
        hv[1] = (bf16_t)fmaxf(v[1] + bi.y, 0.f);
        hv[2] = (bf16_t)fmaxf(v[2] + bi.z, 0.f);
        hv[3] = (bf16_t)fmaxf(v[3] + bi.w, 0.f);
        *(bf16x4*)&hrow[f] = hv;
      }
    }
  } else {
    float* finalp = (float*)outp;
#pragma unroll
    for (int nj = 0; nj < 4; ++nj) {
      int c = c0 + wn * 64 + nj * 16 + l15;
      if (c < cnt) {
        int tok = inv[e * CAP + c];
        float r = rpm[tok];
        float* orow = finalp + (size_t)tok * DDIM;
#pragma unroll
        for (int mi = 0; mi < 4; ++mi) {
          int dd = m0 + wm * 64 + mi * 16 + l4 * 4;
          const float4 bi = *(const float4*)&bias[dd];
          f32x4 v = acc[mi][nj];
          float4 o;
          o.x = (v[0] + bi.x) * r;
          o.y = (v[1] + bi.y) * r;
          o.z = (v[2] + bi.z) * r;
          o.w = (v[3] + bi.w) * r;
          *(float4*)&orow[dd] = o;
        }
      }
    }
  }
}

// ---------------- host launcher ----------------
extern "C" void kernel_launch(void* const* d_in, const int* in_sizes, int n_in,
                              void* d_out, int out_size, void* d_ws, size_t ws_size,
                              hipStream_t stream) {
  (void)in_sizes; (void)n_in; (void)out_size;
  const float* x   = (const float*)d_in[0];
  const float* wsw = (const float*)d_in[1];
  const float* bsw = (const float*)d_in[2];
  const float* W1  = (const float*)d_in[3];
  const float* b1  = (const float*)d_in[4];
  const float* W2  = (const float*)d_in[5];
  const float* b2  = (const float*)d_in[6];

  float* out_final  = (float*)d_out;            // [T][D]
  float* out_counts = out_final + 8388608;      // [8]
  float* out_rps    = out_final + 8388616;      // [8]
  float* out_ndrop  = out_final + 8388624;      // [1]
  float* out_rpm    = out_final + 8388625;      // [T] (output 5 of reference)

  char* ws = (char*)d_ws;
  size_t off = 0;
  auto carve = [&](size_t bytes) {
    char* p = ws + off;
    off += (bytes + 255) & ~(size_t)255;
    return p;
  };
  bf16_t* xbf      = (bf16_t*)carve((size_t)T_TOK * DDIM * 2);   // 16 MB
  int*    routes   = (int*)   carve((size_t)T_TOK * 4);
  int*    inv      = (int*)   carve((size_t)NEXP * CAP * 4);
  int*    counts_i = (int*)   carve((size_t)NEXP * 4);
  float*  partial  = (float*) carve((size_t)2048 * 8 * 4);
  int*    drop_list= (int*)   carve((size_t)T_TOK * 4);
  int*    ndrop_i  = (int*)   carve(256);
  size_t fixed = off;
  const size_t PER_E = 2 * (size_t)FDIM * DDIM * 2 + (size_t)CAP * FDIM * 2; // 32MB
  int nb = 8;
  while (nb > 1 && fixed + (size_t)nb * PER_E > ws_size) nb >>= 1;
  bf16_t* W1T  = (bf16_t*)carve((size_t)nb * FDIM * DDIM * 2);
  bf16_t* W2T  = (bf16_t*)carve((size_t)nb * DDIM * FDIM * 2);
  bf16_t* hbuf = (bf16_t*)carve((size_t)nb * CAP * FDIM * 2);

  router_kernel<<<T_TOK / 4, 256, 0, stream>>>(x, wsw, bsw, routes, out_rpm, partial, xbf);
  reduce_partials_kernel<<<1, 256, 0, stream>>>(partial, out_rps);
  scan_kernel<<<1, 256, 0, stream>>>(routes, inv, counts_i, out_counts, out_ndrop,
                                     drop_list, ndrop_i);
  fill_dropped_kernel<<<256, 256, 0, stream>>>(drop_list, ndrop_i, x, out_rpm, out_final);

  for (int e0 = 0; e0 < NEXP; e0 += nb) {
    transpose_both_kernel<<<dim3(64, 16, 2 * nb), 256, 0, stream>>>(W1, W2, W1T, W2T, nb, e0);
    gemm_kernel<DDIM, 1><<<dim3(CAP / 128, FDIM / 128, nb), 256, 0, stream>>>(
        W1T, xbf, inv, counts_i, b1, nullptr, hbuf, e0);
    gemm_kernel<FDIM, 2><<<dim3(CAP / 128, DDIM / 128, nb), 256, 0, stream>>>(
        W2T, hbuf, inv, counts_i, b2, out_rpm, d_out, e0);
  }
}

// Round 10
// 406.950 us; speedup vs baseline: 1.1664x; 1.0291x over previous
//
#include <hip/hip_runtime.h>
#include <hip/hip_bf16.h>
#include <cstdint>
#include <cstddef>

// Problem constants (fixed by reference)
#define T_TOK 8192
#define DDIM  1024
#define FDIM  4096
#define NEXP  8
#define CAP   2048   // int(2.0 * T / E)

typedef __bf16 bf16_t;
typedef __bf16 bf16x8 __attribute__((ext_vector_type(8)));
typedef __bf16 bf16x4 __attribute__((ext_vector_type(4)));
typedef float  f32x4  __attribute__((ext_vector_type(4)));

// async global->LDS: lds dest must be WAVE-UNIFORM base; HW adds lane*16
__device__ __forceinline__ void gload16(const void* g, void* l) {
  __builtin_amdgcn_global_load_lds(
      (const __attribute__((address_space(1))) unsigned int*)g,
      (__attribute__((address_space(3))) unsigned int*)l,
      16, 0, 0);
}

#define VMWAIT(N) asm volatile("s_waitcnt vmcnt(" #N ")" ::: "memory")
#define BARR asm volatile("s_barrier" ::: "memory")

// ---------------- router: logits/softmax/argmax + x->bf16 ----------------
__global__ void router_kernel(const float* __restrict__ x, const float* __restrict__ wsw,
                              const float* __restrict__ bsw, int* __restrict__ routes,
                              float* __restrict__ rpm, float* __restrict__ partial,
                              bf16_t* __restrict__ xbf) {
  const int wv = threadIdx.x >> 6, lane = threadIdx.x & 63;
  const int t = blockIdx.x * 4 + wv;
  const float4* xr = (const float4*)(x + (size_t)t * DDIM);
  float4 xv[4];
  float a[8] = {0.f,0.f,0.f,0.f,0.f,0.f,0.f,0.f};
#pragma unroll
  for (int p = 0; p < 4; ++p) {
    xv[p] = xr[lane + p * 64];
#pragma unroll
    for (int j = 0; j < 4; ++j) {
      float v = ((const float*)&xv[p])[j];
      int d = (lane + p * 64) * 4 + j;
      const float4* wr = (const float4*)(wsw + d * 8);
      float4 w0 = wr[0], w1 = wr[1];
      a[0] += v * w0.x; a[1] += v * w0.y; a[2] += v * w0.z; a[3] += v * w0.w;
      a[4] += v * w1.x; a[5] += v * w1.y; a[6] += v * w1.z; a[7] += v * w1.w;
    }
  }
#pragma unroll
  for (int e = 0; e < 8; ++e) {
#pragma unroll
    for (int off = 32; off > 0; off >>= 1) a[e] += __shfl_xor(a[e], off);
    a[e] += bsw[e];
  }
  float m = a[0]; int arg = 0;
#pragma unroll
  for (int e = 1; e < 8; ++e) { if (a[e] > m) { m = a[e]; arg = e; } }
  float p8[8]; float s = 0.f;
#pragma unroll
  for (int e = 0; e < 8; ++e) { p8[e] = expf(a[e] - m); s += p8[e]; }
  float inv_s = 1.f / s;   // = softmax max since p[arg]=1
  bf16_t* xbr = xbf + (size_t)t * DDIM;
#pragma unroll
  for (int p = 0; p < 4; ++p) {
    int i4 = lane + p * 64;
    bf16x4 hb;
    hb[0] = (bf16_t)xv[p].x; hb[1] = (bf16_t)xv[p].y;
    hb[2] = (bf16_t)xv[p].z; hb[3] = (bf16_t)xv[p].w;
    *(bf16x4*)(xbr + (size_t)i4 * 4) = hb;
  }
  __shared__ float pp[4][8];
  if (lane == 0) {
    routes[t] = arg;
    rpm[t] = inv_s;
#pragma unroll
    for (int e = 0; e < 8; ++e) pp[wv][e] = p8[e] * inv_s;
  }
  __syncthreads();
  if (threadIdx.x < 8) {
    int e = threadIdx.x;
    partial[(size_t)blockIdx.x * 8 + e] = pp[0][e] + pp[1][e] + pp[2][e] + pp[3][e];
  }
}

// ---------------- queue-position scan + dispatch index + drop list + rps reduce ----------------
__global__ void scan_kernel(const int* __restrict__ routes, int* __restrict__ inv,
                            int* __restrict__ counts_i, float* __restrict__ out_counts,
                            float* __restrict__ out_ndrop, int* __restrict__ drop_list,
                            int* __restrict__ ndrop_i, const float* __restrict__ partial,
                            float* __restrict__ out_rps) {
  __shared__ int scnt[256][8];
  __shared__ int raw[8];
  __shared__ int dropc;
  __shared__ float red[256];
  int tid = threadIdx.x;
  for (int i = tid; i < NEXP * CAP; i += 256) inv[i] = 0;   // zero (incl. padded tail)
  if (tid == 0) dropc = 0;
  int myr[32];
  int cnt[8] = {0,0,0,0,0,0,0,0};
  int tbase = tid * 32;
  for (int i = 0; i < 32; ++i) { int r = routes[tbase + i]; myr[i] = r; cnt[r]++; }
#pragma unroll
  for (int e = 0; e < 8; ++e) scnt[tid][e] = cnt[e];
  __syncthreads();
  if (tid < 8) {
    int run = 0;
    for (int j = 0; j < 256; ++j) { int v = scnt[j][tid]; scnt[j][tid] = run; run += v; }
    raw[tid] = run;
  }
  __syncthreads();
  int base[8];
#pragma unroll
  for (int e = 0; e < 8; ++e) base[e] = scnt[tid][e];
  for (int i = 0; i < 32; ++i) {
    int r = myr[i];
    int p = base[r]++;
    if (p < CAP) inv[r * CAP + p] = tbase + i;
    else         drop_list[atomicAdd(&dropc, 1)] = tbase + i;
  }
  if (tid < 8) {
    int c = min(raw[tid], CAP);
    counts_i[tid] = c;
    out_counts[tid] = (float)c;
  }
  __syncthreads();
  if (tid == 0) {
    *ndrop_i = dropc;
    *out_ndrop = (float)dropc;
  }
  // deterministic route_prob_sums reduction (was reduce_partials_kernel)
  {
    int e2 = tid & 7, j0 = tid >> 3;
    float s = 0.f;
    for (int j = j0; j < 2048; j += 32) s += partial[j * 8 + e2];
    red[tid] = s;
    __syncthreads();
    if (tid < 8) {
      float tt = 0.f;
      for (int k = 0; k < 32; ++k) tt += red[tid + 8 * k];
      out_rps[tid] = tt;
    }
  }
}

// ---------------- fill only dropped tokens: out[t] = x[t]*rpm[t] ----------------
__global__ void fill_dropped_kernel(const int* __restrict__ drop_list, const int* __restrict__ ndrop_i,
                                    const float* __restrict__ x, const float* __restrict__ rpm,
                                    float* __restrict__ outf) {
  int total = (*ndrop_i) * 256;    // float4s per dropped token row
  for (int i = blockIdx.x * blockDim.x + threadIdx.x; i < total; i += gridDim.x * blockDim.x) {
    int t = drop_list[i >> 8];
    int j = i & 255;
    float r = rpm[t];
    float4 v = ((const float4*)(x + (size_t)t * DDIM))[j];
    float4 o = {v.x * r, v.y * r, v.z * r, v.w * r};
    ((float4*)(outf + (size_t)t * DDIM))[j] = o;
  }
}

// ---------------- fused transpose+convert for W1 and W2 in one launch ----------------
__global__ void transpose_both_kernel(const float* __restrict__ W1, const float* __restrict__ W2,
                                      bf16_t* __restrict__ W1T, bf16_t* __restrict__ W2T,
                                      int nb, int e0) {
  const int z = blockIdx.z;
  const float* s; bf16_t* d; int R, C, bx, by;
  if (z < nb) {
    s = W1 + (size_t)(e0 + z) * ((size_t)DDIM * FDIM);
    d = W1T + (size_t)z * ((size_t)DDIM * FDIM);
    R = DDIM; C = FDIM; bx = blockIdx.x * 64; by = blockIdx.y * 64;
  } else {
    s = W2 + (size_t)(e0 + z - nb) * ((size_t)FDIM * DDIM);
    d = W2T + (size_t)(z - nb) * ((size_t)FDIM * DDIM);
    R = FDIM; C = DDIM; bx = blockIdx.y * 64; by = blockIdx.x * 64;
  }
  __shared__ float tile[64][65];
  int c4 = (threadIdx.x & 15) * 4;
  int r0 = threadIdx.x >> 4;
#pragma unroll
  for (int p = 0; p < 4; ++p) {
    int r = r0 + p * 16;
    float4 v = *(const float4*)&s[(size_t)(by + r) * C + bx + c4];
    tile[r][c4] = v.x; tile[r][c4 + 1] = v.y; tile[r][c4 + 2] = v.z; tile[r][c4 + 3] = v.w;
  }
  __syncthreads();
  int r8 = (threadIdx.x & 7) * 8;
  int cw = threadIdx.x >> 3;
#pragma unroll
  for (int p = 0; p < 2; ++p) {
    int c = cw + p * 32;
    bf16x8 o;
#pragma unroll
    for (int j = 0; j < 8; ++j) o[j] = (bf16_t)tile[r8 + j][c];
    *(bf16x8*)&d[(size_t)(bx + c) * R + by + r8] = o;
  }
}

// ============ MFMA GEMM: 128x128 tile, BK=32, 4 waves, 4 blocks/CU ============
// D[m][c] = sum_k A[m][k]*B[c][k] (row-major K-contiguous operands).
// 4 waves 2M x 2N, per-wave 64x64 = 4x4 frags of 16x16. LDS 32KB static:
//   A [2dbuf][128 rows][64B] (16KB) then B [2dbuf][128 cols][64B] (16KB).
// R9's free-slip skeleton: stage(t+1) into dead dbuf at tile start; ONE
// vmcnt(0)+s_barrier per K-tile; no intra-tile barriers -> waves slip and the
// 4 resident blocks (32KB LDS, launch_bounds(256,4), ~110 VGPR) overlap each
// other's latency (m97/m114 mechanism). Hazards: WAR - stage targets dbuf whose
// reads all completed before the previous barrier; RAW - per-wave vmcnt(0)
// drain + barrier publishes DMA writes to all waves (R9-verified).
// Swizzle: 16B slot s at row r holds K-granule s^((r>>1)&3); frag reads use
// slot (l4)^((r>>1)&3) -> 2-way bank aliasing (free, m136).
// Stage map: unit u (4KB = 64 rows): thread tid -> row u*64+(tid>>2), slot
// tid&3, LDS byte u*4096 + tid*16 (= wave-uniform u*4096+w*1024, HW +lane*16).
// MODE 1: A=W1T[F][D], B=xbf gathered via inv -> relu(+b1) -> h bf16
// MODE 2: A=W2T[D][F], B=h                    -> (+b2)*rpm scattered -> final f32
template <int KDIM, int MODE>
__launch_bounds__(256, 4)
__global__ void gemm_kernel(const bf16_t* __restrict__ Abase, const bf16_t* __restrict__ Bbase,
                            const int* __restrict__ inv, const int* __restrict__ counts_i,
                            const float* __restrict__ bias_all, const float* __restrict__ rpm,
                            void* __restrict__ outp, int e0) {
  constexpr int MDIM = (MODE == 1) ? FDIM : DDIM;
  constexpr int NT = KDIM / 32;
  __shared__ __align__(16) char smem[32768];

  // T1: XCD-chunked bijective swizzle (nwg % 8 == 0 by construction)
  const int nx = gridDim.x, ny = gridDim.y;
  const int nwg = nx * ny * gridDim.z;
  const int flat = blockIdx.x + nx * (blockIdx.y + ny * blockIdx.z);
  const int nf = (flat & 7) * (nwg >> 3) + (flat >> 3);
  const int bx = nf % nx;
  const int tmp = nf / nx;
  const int by = tmp % ny, bz = tmp / ny;

  const int e = e0 + bz;
  const int cnt = counts_i[e];
  const int c0 = bx * 128;
  if (c0 >= cnt) return;                 // uniform early-exit before any barrier
  const int m0 = by * 128;

  const bf16_t* A = Abase + (size_t)bz * ((size_t)MDIM * KDIM);
  const float* bias = bias_all + (size_t)e * MDIM;

  const int tid = threadIdx.x, lane = tid & 63, w = tid >> 6;
  const int l15 = lane & 15, l4 = lane >> 4;
  const int wm = w >> 1, wn = w & 1;

  // ---- stage sources (pre-swizzled global element offsets / pointers) ----
  size_t aOff[2];
#pragma unroll
  for (int u = 0; u < 2; ++u) {
    int r = u * 64 + (tid >> 2);
    int g = (tid & 3) ^ ((r >> 1) & 3);
    aOff[u] = (size_t)(m0 + r) * KDIM + g * 8;
  }
  const bf16_t* bPtr[2];
#pragma unroll
  for (int v = 0; v < 2; ++v) {
    int c = v * 64 + (tid >> 2);
    int g = (tid & 3) ^ ((c >> 1) & 3);
    if (MODE == 1) {
      int tok = inv[e * CAP + c0 + c];   // zeroed tail -> token 0 (result unread)
      bPtr[v] = Bbase + (size_t)tok * KDIM + g * 8;
    } else {
      bPtr[v] = Bbase + (size_t)bz * ((size_t)CAP * KDIM) + (size_t)(c0 + c) * KDIM + g * 8;
    }
  }

  // ---- swizzled read offsets (within dbuf region) ----
  int aRd[4], bRd[4];
#pragma unroll
  for (int mi = 0; mi < 4; ++mi) {
    int r = wm * 64 + mi * 16 + l15;
    aRd[mi] = r * 64 + ((l4 ^ ((r >> 1) & 3)) << 4);
  }
#pragma unroll
  for (int nj = 0; nj < 4; ++nj) {
    int c = wn * 64 + nj * 16 + l15;
    bRd[nj] = c * 64 + ((l4 ^ ((c >> 1) & 3)) << 4);
  }

  auto stage = [&](int t) {
    char* sa = smem + (t & 1) * 8192 + w * 1024;
    char* sb = smem + 16384 + (t & 1) * 8192 + w * 1024;
#pragma unroll
    for (int u = 0; u < 2; ++u) gload16(A + aOff[u] + t * 32, sa + u * 4096);
#pragma unroll
    for (int v = 0; v < 2; ++v) gload16(bPtr[v] + t * 32, sb + v * 4096);
  };

  f32x4 acc[4][4];
#pragma unroll
  for (int i = 0; i < 4; ++i)
#pragma unroll
    for (int j = 0; j < 4; ++j) acc[i][j] = (f32x4){0.f, 0.f, 0.f, 0.f};

  // prologue: stage tile 0, drain, publish
  stage(0);
  VMWAIT(0);
  BARR;

  for (int t = 0; t < NT; ++t) {
    const int d = t & 1;
    const bool more = (t + 1 < NT);
    if (more) stage(t + 1);              // into dead dbuf d^1
    const char* sa = smem + d * 8192;
    const char* sb = smem + 16384 + d * 8192;
    bf16x8 af[4], bf[4];
#pragma unroll
    for (int mi = 0; mi < 4; ++mi) af[mi] = *(const bf16x8*)(sa + aRd[mi]);
#pragma unroll
    for (int nj = 0; nj < 4; ++nj) bf[nj] = *(const bf16x8*)(sb + bRd[nj]);
#pragma unroll
    for (int mi = 0; mi < 4; ++mi)
#pragma unroll
      for (int nj = 0; nj < 4; ++nj)
        acc[mi][nj] = __builtin_amdgcn_mfma_f32_16x16x32_bf16(af[mi], bf[nj], acc[mi][nj], 0, 0, 0);
    if (more) {
      VMWAIT(0);                         // drains stage(t+1), issued one tile ago
      BARR;                              // publish to all waves
    }
  }

  // ---- epilogue: D layout col=lane&15, row=(lane>>4)*4+reg [verified m89/m91] ----
  if constexpr (MODE == 1) {
    bf16_t* h = (bf16_t*)outp + (size_t)bz * ((size_t)CAP * FDIM);
#pragma unroll
    for (int nj = 0; nj < 4; ++nj) {
      int c = c0 + wn * 64 + nj * 16 + l15;
      bf16_t* hrow = h + (size_t)c * FDIM;
#pragma unroll
      for (int mi = 0; mi < 4; ++mi) {
        int f = m0 + wm * 64 + mi * 16 + l4 * 4;
        const float4 bi = *(const float4*)&bias[f];
        f32x4 v = acc[mi][nj];
        bf16x4 hv;
        hv[0] = (bf16_t)fmaxf(v[0] + bi.x, 0.f);
        hv[1] = (bf16_t)fmaxf(v[1] + bi.y, 0.f);
        hv[2] = (bf16_t)fmaxf(v[2] + bi.z, 0.f);
        hv[3] = (bf16_t)fmaxf(v[3] + bi.w, 0.f);
        *(bf16x4*)&hrow[f] = hv;
      }
    }
  } else {
    float* finalp = (float*)outp;
#pragma unroll
    for (int nj = 0; nj < 4; ++nj) {
      int c = c0 + wn * 64 + nj * 16 + l15;
      if (c < cnt) {
        int tok = inv[e * CAP + c];
        float r = rpm[tok];
        float* orow = finalp + (size_t)tok * DDIM;
#pragma unroll
        for (int mi = 0; mi < 4; ++mi) {
          int dd = m0 + wm * 64 + mi * 16 + l4 * 4;
          const float4 bi = *(const float4*)&bias[dd];
          f32x4 v = acc[mi][nj];
          float4 o;
          o.x = (v[0] + bi.x) * r;
          o.y = (v[1] + bi.y) * r;
          o.z = (v[2] + bi.z) * r;
          o.w = (v[3] + bi.w) * r;
          *(float4*)&orow[dd] = o;
        }
      }
    }
  }
}

// ---------------- host launcher ----------------
extern "C" void kernel_launch(void* const* d_in, const int* in_sizes, int n_in,
                              void* d_out, int out_size, void* d_ws, size_t ws_size,
                              hipStream_t stream) {
  (void)in_sizes; (void)n_in; (void)out_size;
  const float* x   = (const float*)d_in[0];
  const float* wsw = (const float*)d_in[1];
  const float* bsw = (const float*)d_in[2];
  const float* W1  = (const float*)d_in[3];
  const float* b1  = (const float*)d_in[4];
  const float* W2  = (const float*)d_in[5];
  const float* b2  = (const float*)d_in[6];

  float* out_final  = (float*)d_out;            // [T][D]
  float* out_counts = out_final + 8388608;      // [8]
  float* out_rps    = out_final + 8388616;      // [8]
  float* out_ndrop  = out_final + 8388624;      // [1]
  float* out_rpm    = out_final + 8388625;      // [T] (output 5 of reference)

  char* ws = (char*)d_ws;
  size_t off = 0;
  auto carve = [&](size_t bytes) {
    char* p = ws + off;
    off += (bytes + 255) & ~(size_t)255;
    return p;
  };
  bf16_t* xbf      = (bf16_t*)carve((size_t)T_TOK * DDIM * 2);   // 16 MB
  int*    routes   = (int*)   carve((size_t)T_TOK * 4);
  int*    inv      = (int*)   carve((size_t)NEXP * CAP * 4);
  int*    counts_i = (int*)   carve((size_t)NEXP * 4);
  float*  partial  = (float*) carve((size_t)2048 * 8 * 4);
  int*    drop_list= (int*)   carve((size_t)T_TOK * 4);
  int*    ndrop_i  = (int*)   carve(256);
  size_t fixed = off;
  const size_t PER_E = 2 * (size_t)FDIM * DDIM * 2 + (size_t)CAP * FDIM * 2; // 32MB
  int nb = 8;
  while (nb > 1 && fixed + (size_t)nb * PER_E > ws_size) nb >>= 1;
  bf16_t* W1T  = (bf16_t*)carve((size_t)nb * FDIM * DDIM * 2);
  bf16_t* W2T  = (bf16_t*)carve((size_t)nb * DDIM * FDIM * 2);
  bf16_t* hbuf = (bf16_t*)carve((size_t)nb * CAP * FDIM * 2);

  router_kernel<<<T_TOK / 4, 256, 0, stream>>>(x, wsw, bsw, routes, out_rpm, partial, xbf);
  scan_kernel<<<1, 256, 0, stream>>>(routes, inv, counts_i, out_counts, out_ndrop,
                                     drop_list, ndrop_i, partial, out_rps);
  fill_dropped_kernel<<<256, 256, 0, stream>>>(drop_list, ndrop_i, x, out_rpm, out_final);

  for (int e0 = 0; e0 < NEXP; e0 += nb) {
    transpose_both_kernel<<<dim3(64, 16, 2 * nb), 256, 0, stream>>>(W1, W2, W1T, W2T, nb, e0);
    gemm_kernel<DDIM, 1><<<dim3(CAP / 128, FDIM / 128, nb), 256, 0, stream>>>(
        W1T, xbf, inv, counts_i, b1, nullptr, hbuf, e0);
    gemm_kernel<FDIM, 2><<<dim3(CAP / 128, DDIM / 128, nb), 256, 0, stream>>>(
        W2T, hbuf, inv, counts_i, b2, out_rpm, d_out, e0);
  }
}

// Round 11
// 383.189 us; speedup vs baseline: 1.2387x; 1.0620x over previous
//
#include <hip/hip_runtime.h>
#include <hip/hip_bf16.h>
#include <cstdint>
#include <cstddef>

// Problem constants (fixed by reference)
#define T_TOK 8192
#define DDIM  1024
#define FDIM  4096
#define NEXP  8
#define CAP   2048   // int(2.0 * T / E)

typedef __bf16 bf16_t;
typedef __bf16 bf16x8 __attribute__((ext_vector_type(8)));
typedef __bf16 bf16x4 __attribute__((ext_vector_type(4)));
typedef float  f32x4  __attribute__((ext_vector_type(4)));

// async global->LDS: lds dest must be WAVE-UNIFORM base; HW adds lane*16
__device__ __forceinline__ void gload16(const void* g, void* l) {
  __builtin_amdgcn_global_load_lds(
      (const __attribute__((address_space(1))) unsigned int*)g,
      (__attribute__((address_space(3))) unsigned int*)l,
      16, 0, 0);
}

#define VMWAIT(N) asm volatile("s_waitcnt vmcnt(" #N ")" ::: "memory")
#define BARR asm volatile("s_barrier" ::: "memory")

// ---------------- router: logits/softmax/argmax + x->bf16 ----------------
__global__ void router_kernel(const float* __restrict__ x, const float* __restrict__ wsw,
                              const float* __restrict__ bsw, int* __restrict__ routes,
                              float* __restrict__ rpm, float* __restrict__ partial,
                              bf16_t* __restrict__ xbf) {
  const int wv = threadIdx.x >> 6, lane = threadIdx.x & 63;
  const int t = blockIdx.x * 4 + wv;
  const float4* xr = (const float4*)(x + (size_t)t * DDIM);
  float4 xv[4];
  float a[8] = {0.f,0.f,0.f,0.f,0.f,0.f,0.f,0.f};
#pragma unroll
  for (int p = 0; p < 4; ++p) {
    xv[p] = xr[lane + p * 64];
#pragma unroll
    for (int j = 0; j < 4; ++j) {
      float v = ((const float*)&xv[p])[j];
      int d = (lane + p * 64) * 4 + j;
      const float4* wr = (const float4*)(wsw + d * 8);
      float4 w0 = wr[0], w1 = wr[1];
      a[0] += v * w0.x; a[1] += v * w0.y; a[2] += v * w0.z; a[3] += v * w0.w;
      a[4] += v * w1.x; a[5] += v * w1.y; a[6] += v * w1.z; a[7] += v * w1.w;
    }
  }
#pragma unroll
  for (int e = 0; e < 8; ++e) {
#pragma unroll
    for (int off = 32; off > 0; off >>= 1) a[e] += __shfl_xor(a[e], off);
    a[e] += bsw[e];
  }
  float m = a[0]; int arg = 0;
#pragma unroll
  for (int e = 1; e < 8; ++e) { if (a[e] > m) { m = a[e]; arg = e; } }
  float p8[8]; float s = 0.f;
#pragma unroll
  for (int e = 0; e < 8; ++e) { p8[e] = expf(a[e] - m); s += p8[e]; }
  float inv_s = 1.f / s;   // = softmax max since p[arg]=1
  bf16_t* xbr = xbf + (size_t)t * DDIM;
#pragma unroll
  for (int p = 0; p < 4; ++p) {
    int i4 = lane + p * 64;
    bf16x4 hb;
    hb[0] = (bf16_t)xv[p].x; hb[1] = (bf16_t)xv[p].y;
    hb[2] = (bf16_t)xv[p].z; hb[3] = (bf16_t)xv[p].w;
    *(bf16x4*)(xbr + (size_t)i4 * 4) = hb;
  }
  __shared__ float pp[4][8];
  if (lane == 0) {
    routes[t] = arg;
    rpm[t] = inv_s;
#pragma unroll
    for (int e = 0; e < 8; ++e) pp[wv][e] = p8[e] * inv_s;
  }
  __syncthreads();
  if (threadIdx.x < 8) {
    int e = threadIdx.x;
    partial[(size_t)blockIdx.x * 8 + e] = pp[0][e] + pp[1][e] + pp[2][e] + pp[3][e];
  }
}

// ---------------- queue-position scan + dispatch index + drop list + rps reduce ----------------
__global__ void scan_kernel(const int* __restrict__ routes, int* __restrict__ inv,
                            int* __restrict__ counts_i, float* __restrict__ out_counts,
                            float* __restrict__ out_ndrop, int* __restrict__ drop_list,
                            int* __restrict__ ndrop_i, const float* __restrict__ partial,
                            float* __restrict__ out_rps) {
  __shared__ int scnt[256][8];
  __shared__ int raw[8];
  __shared__ int dropc;
  __shared__ float red[256];
  int tid = threadIdx.x;
  for (int i = tid; i < NEXP * CAP; i += 256) inv[i] = 0;   // zero (incl. padded tail)
  if (tid == 0) dropc = 0;
  int myr[32];
  int cnt[8] = {0,0,0,0,0,0,0,0};
  int tbase = tid * 32;
  for (int i = 0; i < 32; ++i) { int r = routes[tbase + i]; myr[i] = r; cnt[r]++; }
#pragma unroll
  for (int e = 0; e < 8; ++e) scnt[tid][e] = cnt[e];
  __syncthreads();
  if (tid < 8) {
    int run = 0;
    for (int j = 0; j < 256; ++j) { int v = scnt[j][tid]; scnt[j][tid] = run; run += v; }
    raw[tid] = run;
  }
  __syncthreads();
  int base[8];
#pragma unroll
  for (int e = 0; e < 8; ++e) base[e] = scnt[tid][e];
  for (int i = 0; i < 32; ++i) {
    int r = myr[i];
    int p = base[r]++;
    if (p < CAP) inv[r * CAP + p] = tbase + i;
    else         drop_list[atomicAdd(&dropc, 1)] = tbase + i;
  }
  if (tid < 8) {
    int c = min(raw[tid], CAP);
    counts_i[tid] = c;
    out_counts[tid] = (float)c;
  }
  __syncthreads();
  if (tid == 0) {
    *ndrop_i = dropc;
    *out_ndrop = (float)dropc;
  }
  // deterministic route_prob_sums reduction
  {
    int e2 = tid & 7, j0 = tid >> 3;
    float s = 0.f;
    for (int j = j0; j < 2048; j += 32) s += partial[j * 8 + e2];
    red[tid] = s;
    __syncthreads();
    if (tid < 8) {
      float tt = 0.f;
      for (int k = 0; k < 32; ++k) tt += red[tid + 8 * k];
      out_rps[tid] = tt;
    }
  }
}

// ---------------- fill only dropped tokens: out[t] = x[t]*rpm[t] ----------------
__global__ void fill_dropped_kernel(const int* __restrict__ drop_list, const int* __restrict__ ndrop_i,
                                    const float* __restrict__ x, const float* __restrict__ rpm,
                                    float* __restrict__ outf) {
  int total = (*ndrop_i) * 256;    // float4s per dropped token row
  for (int i = blockIdx.x * blockDim.x + threadIdx.x; i < total; i += gridDim.x * blockDim.x) {
    int t = drop_list[i >> 8];
    int j = i & 255;
    float r = rpm[t];
    float4 v = ((const float4*)(x + (size_t)t * DDIM))[j];
    float4 o = {v.x * r, v.y * r, v.z * r, v.w * r};
    ((float4*)(outf + (size_t)t * DDIM))[j] = o;
  }
}

// ---------------- fused transpose+convert for W1 and W2 in one launch ----------------
__global__ void transpose_both_kernel(const float* __restrict__ W1, const float* __restrict__ W2,
                                      bf16_t* __restrict__ W1T, bf16_t* __restrict__ W2T,
                                      int nb, int e0) {
  const int z = blockIdx.z;
  const float* s; bf16_t* d; int R, C, bx, by;
  if (z < nb) {
    s = W1 + (size_t)(e0 + z) * ((size_t)DDIM * FDIM);
    d = W1T + (size_t)z * ((size_t)DDIM * FDIM);
    R = DDIM; C = FDIM; bx = blockIdx.x * 64; by = blockIdx.y * 64;
  } else {
    s = W2 + (size_t)(e0 + z - nb) * ((size_t)FDIM * DDIM);
    d = W2T + (size_t)(z - nb) * ((size_t)FDIM * DDIM);
    R = FDIM; C = DDIM; bx = blockIdx.y * 64; by = blockIdx.x * 64;
  }
  __shared__ float tile[64][65];
  int c4 = (threadIdx.x & 15) * 4;
  int r0 = threadIdx.x >> 4;
#pragma unroll
  for (int p = 0; p < 4; ++p) {
    int r = r0 + p * 16;
    float4 v = *(const float4*)&s[(size_t)(by + r) * C + bx + c4];
    tile[r][c4] = v.x; tile[r][c4 + 1] = v.y; tile[r][c4 + 2] = v.z; tile[r][c4 + 3] = v.w;
  }
  __syncthreads();
  int r8 = (threadIdx.x & 7) * 8;
  int cw = threadIdx.x >> 3;
#pragma unroll
  for (int p = 0; p < 2; ++p) {
    int c = cw + p * 32;
    bf16x8 o;
#pragma unroll
    for (int j = 0; j < 8; ++j) o[j] = (bf16_t)tile[r8 + j][c];
    *(bf16x8*)&d[(size_t)(bx + c) * R + by + r8] = o;
  }
}

// ============ MFMA GEMM: 128x128 tile, BK=32, 4 waves, 3-slot ring, depth-2 prefetch ============
// D[m][c] = sum_k A[m][k]*B[c][k] (row-major K-contiguous operands).
// 4 waves 2M x 2N, per-wave 64x64 = 4x4 frags of 16x16. LDS 48KB static:
//   slot s (s = t % 3, 16KB): A [128 rows][64B] (8KB) then B [128 cols][64B] (8KB).
// Per tile t: VMWAIT(4) [retires stage(t); stage(t+1) stays in flight] -> s_barrier
// [publishes all waves' DMA for t; joins compute(t-1)] -> stage(t+2) [slot (t+2)%3
// == (t-1)%3, reads done pre-barrier] -> ds_read+16 MFMA, no second barrier ->
// waves slip. Issue->wait distance = 2 tile bodies (~700-900cy) covers L3/HBM.
// 3 blocks/CU (48KB LDS, launch_bounds(256,3)) overlap each other's residual stalls.
// Swizzle: 16B slot s at row r holds K-granule s^((r>>1)&3); reads use
// l4^((r>>1)&3) -> 2-way bank aliasing (free, m136).  [R10-verified mapping]
// MODE 1: A=W1T[F][D], B=xbf gathered via inv -> relu(+b1) -> h bf16
// MODE 2: A=W2T[D][F], B=h                    -> (+b2)*rpm scattered -> final f32
template <int KDIM, int MODE>
__launch_bounds__(256, 3)
__global__ void gemm_kernel(const bf16_t* __restrict__ Abase, const bf16_t* __restrict__ Bbase,
                            const int* __restrict__ inv, const int* __restrict__ counts_i,
                            const float* __restrict__ bias_all, const float* __restrict__ rpm,
                            void* __restrict__ outp, int e0) {
  constexpr int MDIM = (MODE == 1) ? FDIM : DDIM;
  constexpr int NT = KDIM / 32;
  __shared__ __align__(16) char smem[49152];

  // T1: XCD-chunked bijective swizzle (nwg % 8 == 0 by construction)
  const int nx = gridDim.x, ny = gridDim.y;
  const int nwg = nx * ny * gridDim.z;
  const int flat = blockIdx.x + nx * (blockIdx.y + ny * blockIdx.z);
  const int nf = (flat & 7) * (nwg >> 3) + (flat >> 3);
  const int bx = nf % nx;
  const int tmp = nf / nx;
  const int by = tmp % ny, bz = tmp / ny;

  const int e = e0 + bz;
  const int cnt = counts_i[e];
  const int c0 = bx * 128;
  if (c0 >= cnt) return;                 // uniform early-exit before any barrier
  const int m0 = by * 128;

  const bf16_t* A = Abase + (size_t)bz * ((size_t)MDIM * KDIM);
  const float* bias = bias_all + (size_t)e * MDIM;

  const int tid = threadIdx.x, lane = tid & 63, w = tid >> 6;
  const int l15 = lane & 15, l4 = lane >> 4;
  const int wm = w >> 1, wn = w & 1;

  // ---- stage sources (pre-swizzled global element offsets / pointers) ----
  size_t aOff[2];
#pragma unroll
  for (int u = 0; u < 2; ++u) {
    int r = u * 64 + (tid >> 2);
    int g = (tid & 3) ^ ((r >> 1) & 3);
    aOff[u] = (size_t)(m0 + r) * KDIM + g * 8;
  }
  const bf16_t* bPtr[2];
#pragma unroll
  for (int v = 0; v < 2; ++v) {
    int c = v * 64 + (tid >> 2);
    int g = (tid & 3) ^ ((c >> 1) & 3);
    if (MODE == 1) {
      int tok = inv[e * CAP + c0 + c];   // zeroed tail -> token 0 (result unread)
      bPtr[v] = Bbase + (size_t)tok * KDIM + g * 8;
    } else {
      bPtr[v] = Bbase + (size_t)bz * ((size_t)CAP * KDIM) + (size_t)(c0 + c) * KDIM + g * 8;
    }
  }

  // ---- swizzled read offsets (within slot; A at 0, B at +8192) ----
  int aRd[4], bRd[4];
#pragma unroll
  for (int mi = 0; mi < 4; ++mi) {
    int r = wm * 64 + mi * 16 + l15;
    aRd[mi] = r * 64 + ((l4 ^ ((r >> 1) & 3)) << 4);
  }
#pragma unroll
  for (int nj = 0; nj < 4; ++nj) {
    int c = wn * 64 + nj * 16 + l15;
    bRd[nj] = 8192 + c * 64 + ((l4 ^ ((c >> 1) & 3)) << 4);
  }

  auto stage = [&](int t) {
    char* s = smem + (t % 3) * 16384 + w * 1024;
#pragma unroll
    for (int u = 0; u < 2; ++u) gload16(A + aOff[u] + t * 32, s + u * 4096);
#pragma unroll
    for (int v = 0; v < 2; ++v) gload16(bPtr[v] + t * 32, s + 8192 + v * 4096);
  };

  f32x4 acc[4][4];
#pragma unroll
  for (int i = 0; i < 4; ++i)
#pragma unroll
    for (int j = 0; j < 4; ++j) acc[i][j] = (f32x4){0.f, 0.f, 0.f, 0.f};

  // prologue: 2 tiles in flight
  stage(0); stage(1);

  for (int t = 0; t < NT; ++t) {
    if (t + 1 < NT) { VMWAIT(4); } else { VMWAIT(0); }   // retire exactly tile t
    BARR;                                                 // publish + join
    if (t + 2 < NT) stage(t + 2);                         // slot (t+2)%3 == (t-1)%3: dead
    const char* s = smem + (t % 3) * 16384;
    bf16x8 af[4], bf[4];
#pragma unroll
    for (int mi = 0; mi < 4; ++mi) af[mi] = *(const bf16x8*)(s + aRd[mi]);
#pragma unroll
    for (int nj = 0; nj < 4; ++nj) bf[nj] = *(const bf16x8*)(s + bRd[nj]);
#pragma unroll
    for (int mi = 0; mi < 4; ++mi)
#pragma unroll
      for (int nj = 0; nj < 4; ++nj)
        acc[mi][nj] = __builtin_amdgcn_mfma_f32_16x16x32_bf16(af[mi], bf[nj], acc[mi][nj], 0, 0, 0);
  }

  // ---- epilogue: D layout col=lane&15, row=(lane>>4)*4+reg [verified m89/m91] ----
  if constexpr (MODE == 1) {
    bf16_t* h = (bf16_t*)outp + (size_t)bz * ((size_t)CAP * FDIM);
#pragma unroll
    for (int nj = 0; nj < 4; ++nj) {
      int c = c0 + wn * 64 + nj * 16 + l15;
      bf16_t* hrow = h + (size_t)c * FDIM;
#pragma unroll
      for (int mi = 0; mi < 4; ++mi) {
        int f = m0 + wm * 64 + mi * 16 + l4 * 4;
        const float4 bi = *(const float4*)&bias[f];
        f32x4 v = acc[mi][nj];
        bf16x4 hv;
        hv[0] = (bf16_t)fmaxf(v[0] + bi.x, 0.f);
        hv[1] = (bf16_t)fmaxf(v[1] + bi.y, 0.f);
        hv[2] = (bf16_t)fmaxf(v[2] + bi.z, 0.f);
        hv[3] = (bf16_t)fmaxf(v[3] + bi.w, 0.f);
        *(bf16x4*)&hrow[f] = hv;
      }
    }
  } else {
    float* finalp = (float*)outp;
#pragma unroll
    for (int nj = 0; nj < 4; ++nj) {
      int c = c0 + wn * 64 + nj * 16 + l15;
      if (c < cnt) {
        int tok = inv[e * CAP + c];
        float r = rpm[tok];
        float* orow = finalp + (size_t)tok * DDIM;
#pragma unroll
        for (int mi = 0; mi < 4; ++mi) {
          int dd = m0 + wm * 64 + mi * 16 + l4 * 4;
          const float4 bi = *(const float4*)&bias[dd];
          f32x4 v = acc[mi][nj];
          float4 o;
          o.x = (v[0] + bi.x) * r;
          o.y = (v[1] + bi.y) * r;
          o.z = (v[2] + bi.z) * r;
          o.w = (v[3] + bi.w) * r;
          *(float4*)&orow[dd] = o;
        }
      }
    }
  }
}

// ---------------- host launcher ----------------
extern "C" void kernel_launch(void* const* d_in, const int* in_sizes, int n_in,
                              void* d_out, int out_size, void* d_ws, size_t ws_size,
                              hipStream_t stream) {
  (void)in_sizes; (void)n_in; (void)out_size;
  const float* x   = (const float*)d_in[0];
  const float* wsw = (const float*)d_in[1];
  const float* bsw = (const float*)d_in[2];
  const float* W1  = (const float*)d_in[3];
  const float* b1  = (const float*)d_in[4];
  const float* W2  = (const float*)d_in[5];
  const float* b2  = (const float*)d_in[6];

  float* out_final  = (float*)d_out;            // [T][D]
  float* out_counts = out_final + 8388608;      // [8]
  float* out_rps    = out_final + 8388616;      // [8]
  float* out_ndrop  = out_final + 8388624;      // [1]
  float* out_rpm    = out_final + 8388625;      // [T] (output 5 of reference)

  char* ws = (char*)d_ws;
  size_t off = 0;
  auto carve = [&](size_t bytes) {
    char* p = ws + off;
    off += (bytes + 255) & ~(size_t)255;
    return p;
  };
  bf16_t* xbf      = (bf16_t*)carve((size_t)T_TOK * DDIM * 2);   // 16 MB
  int*    routes   = (int*)   carve((size_t)T_TOK * 4);
  int*    inv      = (int*)   carve((size_t)NEXP * CAP * 4);
  int*    counts_i = (int*)   carve((size_t)NEXP * 4);
  float*  partial  = (float*) carve((size_t)2048 * 8 * 4);
  int*    drop_list= (int*)   carve((size_t)T_TOK * 4);
  int*    ndrop_i  = (int*)   carve(256);
  size_t fixed = off;
  const size_t PER_E = 2 * (size_t)FDIM * DDIM * 2 + (size_t)CAP * FDIM * 2; // 32MB
  int nb = 8;
  while (nb > 1 && fixed + (size_t)nb * PER_E > ws_size) nb >>= 1;
  bf16_t* W1T  = (bf16_t*)carve((size_t)nb * FDIM * DDIM * 2);
  bf16_t* W2T  = (bf16_t*)carve((size_t)nb * DDIM * FDIM * 2);
  bf16_t* hbuf = (bf16_t*)carve((size_t)nb * CAP * FDIM * 2);

  router_kernel<<<T_TOK / 4, 256, 0, stream>>>(x, wsw, bsw, routes, out_rpm, partial, xbf);
  scan_kernel<<<1, 256, 0, stream>>>(routes, inv, counts_i, out_counts, out_ndrop,
                                     drop_list, ndrop_i, partial, out_rps);
  fill_dropped_kernel<<<256, 256, 0, stream>>>(drop_list, ndrop_i, x, out_rpm, out_final);

  for (int e0 = 0; e0 < NEXP; e0 += nb) {
    transpose_both_kernel<<<dim3(64, 16, 2 * nb), 256, 0, stream>>>(W1, W2, W1T, W2T, nb, e0);
    gemm_kernel<DDIM, 1><<<dim3(CAP / 128, FDIM / 128, nb), 256, 0, stream>>>(
        W1T, xbf, inv, counts_i, b1, nullptr, hbuf, e0);
    gemm_kernel<FDIM, 2><<<dim3(CAP / 128, DDIM / 128, nb), 256, 0, stream>>>(
        W2T, hbuf, inv, counts_i, b2, out_rpm, d_out, e0);
  }
}